// Round 1
// baseline (2429.836 us; speedup 1.0000x reference)
//
#include <hip/hip_runtime.h>

// 2-layer LSTM recurrence, B=2048 independent sequences, T=1024 + future=64 steps.
// One batch element per 128-thread block (2 waves). Lane j of wave q owns LSTM1
// gate rows {q==0: i(j), g(102+j) ; q==1: f(51+j), o(153+j)} with W_hh1 rows in
// VGPRs. h1[j] lives in lane j; broadcast via v_readlane (SALU). Gate
// activations cross waves through double-buffered LDS (1 barrier/step); the
// c1/h1 update and all of LSTM2 are computed redundantly per wave so h2/c2
// stay replicated in registers.

#define H1N 51
#define WAVE 64

__device__ __forceinline__ float fast_sigmoid(float x) {
    // 1/(1+e^-x); e^-x -> inf gives rcp(inf)=0, e^-x -> 0 gives 1. Safe.
    return __builtin_amdgcn_rcpf(1.0f + __expf(-x));
}
__device__ __forceinline__ float fast_tanh(float x) {
    // tanh = 1 - 2/(e^{2x}+1); safe at both infinities (no inf/inf).
    float e = __expf(2.0f * x);
    return 1.0f - 2.0f * __builtin_amdgcn_rcpf(e + 1.0f);
}

__global__ __launch_bounds__(128, 4)
void lstm_seq(const float* __restrict__ input,   // [B, T]
              const float* __restrict__ W_ih1,   // [204, 1]
              const float* __restrict__ W_hh1,   // [204, 51]
              const float* __restrict__ b_ih1,   // [204]
              const float* __restrict__ b_hh1,   // [204]
              const float* __restrict__ W_ih2,   // [4, 51]
              const float* __restrict__ W_hh2,   // [4, 1]
              const float* __restrict__ b_ih2,   // [4]
              const float* __restrict__ b_hh2,   // [4]
              float* __restrict__ out,           // [B, T+F]
              int T, int TF)
{
    const int tid = threadIdx.x;
    const int wv  = tid >> 6;          // wave id: 0 or 1
    const int j   = tid & (WAVE - 1);  // lane id
    const bool jv = (j < H1N);
    const int b   = blockIdx.x;

    // LSTM1 gate rows handled by this lane (gate order i,f,g,o):
    // wave0: rowA = j (i), rowB = 102+j (g); wave1: rowA = 51+j (f), rowB = 153+j (o)
    const int rowA = wv ? (H1N + j)   : j;
    const int rowB = wv ? (3*H1N + j) : (2*H1N + j);

    // Hot-loop weights in registers. Lanes >= 51 get zeros (benign garbage path).
    float wA[H1N], wB[H1N];
#pragma unroll
    for (int k = 0; k < H1N; ++k) {
        wA[k] = jv ? W_hh1[rowA*H1N + k] : 0.0f;
        wB[k] = jv ? W_hh1[rowB*H1N + k] : 0.0f;
    }
    const float bA  = jv ? (b_ih1[rowA] + b_hh1[rowA]) : 0.0f;
    const float bB  = jv ? (b_ih1[rowB] + b_hh1[rowB]) : 0.0f;
    const float wxA = jv ? W_ih1[rowA] : 0.0f;
    const float wxB = jv ? W_ih1[rowB] : 0.0f;

    // LSTM2: every wave computes all 4 gates (redundant) -> no 2nd barrier.
    float wi2[4];
#pragma unroll
    for (int q = 0; q < 4; ++q) wi2[q] = jv ? W_ih2[q*H1N + j] : 0.0f;
    // These are thread-uniform: compiler keeps them in SGPRs.
    float whh2[4], b2[4];
#pragma unroll
    for (int q = 0; q < 4; ++q) { whh2[q] = W_hh2[q]; b2[q] = b_ih2[q] + b_hh2[q]; }

    // Double-buffered gate activations: [parity][hidden j][gate i,f,g,o]
    __shared__ __align__(16) float act4[2][WAVE][4];

    float h1 = 0.0f, c1 = 0.0f, h2 = 0.0f, c2 = 0.0f;

    const float* __restrict__ xrow = input + (long)b * T;
    float*       __restrict__ orow = out   + (long)b * TF;

    for (int t = 0; t < TF; ++t) {
        float x;
        if (t < T) x = xrow[t];   // uniform -> s_load
        else       x = h2;        // future phase: feed back h2

        // ---- Phase 1: two gate dot-products, h1 broadcast via v_readlane ----
        float accA = fmaf(wxA, x, bA);
        float accB = fmaf(wxB, x, bB);
#pragma unroll
        for (int k = 0; k < H1N; ++k) {
            float h1k = __int_as_float(__builtin_amdgcn_readlane(__float_as_int(h1), k));
            accA = fmaf(wA[k], h1k, accA);
            accB = fmaf(wB[k], h1k, accB);
        }
        float aA, aB;
        if (wv == 0) { aA = fast_sigmoid(accA); aB = fast_tanh(accB); }    // i, g
        else         { aA = fast_sigmoid(accA); aB = fast_sigmoid(accB); } // f, o

        float* buf = &act4[t & 1][0][0];
        buf[j*4 + wv]     = aA;   // slots: wave0 -> 0 (i), wave1 -> 1 (f)
        buf[j*4 + wv + 2] = aB;   //        wave0 -> 2 (g), wave1 -> 3 (o)
        __syncthreads();

        // ---- Phase 2 (redundant in both waves): c1/h1 update ----
        const float4 g = reinterpret_cast<const float4*>(buf)[j];  // i,f,g,o
        c1 = fmaf(g.y, c1, g.x * g.z);     // c1 = f*c1 + i*g
        h1 = g.w * fast_tanh(c1);          // h1 = o*tanh(c1)

        // ---- LSTM2 (H2=1): 4 dots over 51 lanes via butterfly reduce ----
        float p0 = wi2[0] * h1;
        float p1 = wi2[1] * h1;
        float p2 = wi2[2] * h1;
        float p3 = wi2[3] * h1;
#pragma unroll
        for (int m = 1; m < WAVE; m <<= 1) {
            p0 += __shfl_xor(p0, m, WAVE);
            p1 += __shfl_xor(p1, m, WAVE);
            p2 += __shfl_xor(p2, m, WAVE);
            p3 += __shfl_xor(p3, m, WAVE);
        }
        const float g2i = fast_sigmoid(fmaf(whh2[0], h2, b2[0] + p0));
        const float g2f = fast_sigmoid(fmaf(whh2[1], h2, b2[1] + p1));
        const float g2g = fast_tanh  (fmaf(whh2[2], h2, b2[2] + p2));
        const float g2o = fast_sigmoid(fmaf(whh2[3], h2, b2[3] + p3));
        c2 = fmaf(g2f, c2, g2i * g2g);
        h2 = g2o * fast_tanh(c2);

        if (tid == 0) orow[t] = h2;
    }
}

extern "C" void kernel_launch(void* const* d_in, const int* in_sizes, int n_in,
                              void* d_out, int out_size, void* d_ws, size_t ws_size,
                              hipStream_t stream) {
    const float* input = (const float*)d_in[0];
    const float* W_ih1 = (const float*)d_in[1];
    const float* W_hh1 = (const float*)d_in[2];
    const float* b_ih1 = (const float*)d_in[3];
    const float* b_hh1 = (const float*)d_in[4];
    const float* W_ih2 = (const float*)d_in[5];
    const float* W_hh2 = (const float*)d_in[6];
    const float* b_ih2 = (const float*)d_in[7];
    const float* b_hh2 = (const float*)d_in[8];
    float* out = (float*)d_out;

    const int B  = 2048;                 // fixed by setup_inputs()
    const int T  = in_sizes[0] / B;      // 1024
    const int TF = out_size   / B;       // 1088 (T + future)

    lstm_seq<<<dim3(B), dim3(128), 0, stream>>>(
        input, W_ih1, W_hh1, b_ih1, b_hh1, W_ih2, W_hh2, b_ih2, b_hh2,
        out, T, TF);
}